// Round 1
// baseline (184.903 us; speedup 1.0000x reference)
//
#include <hip/hip_runtime.h>
#include <math.h>

#define NBLOCKS 2048
#define NTHREADS 256
#define NWAVES (NTHREADS / 64)

// ---------------------------------------------------------------------------
// Block-wide float sum. Wave=64 shuffle reduce, then LDS across waves.
// Only threadIdx.x==0 holds the full sum on return.
// ---------------------------------------------------------------------------
__device__ __forceinline__ float blockReduceSum(float v) {
    #pragma unroll
    for (int off = 32; off > 0; off >>= 1)
        v += __shfl_down(v, off, 64);
    __shared__ float s[NWAVES];
    const int lane = threadIdx.x & 63;
    const int wid  = threadIdx.x >> 6;
    __syncthreads();                 // protect s[] reuse across calls
    if (lane == 0) s[wid] = v;
    __syncthreads();
    if (wid == 0) {
        v = (lane < NWAVES) ? s[lane] : 0.0f;
        #pragma unroll
        for (int off = NWAVES / 2; off > 0; off >>= 1)
            v += __shfl_down(v, off, 64);
    }
    return v;
}

// ---------------------------------------------------------------------------
// Bonds: E_i = relu((|p0-p1| - eq)^2 - tol^2)
// ---------------------------------------------------------------------------
__global__ __launch_bounds__(NTHREADS) void bond_kernel(
        const float* __restrict__ pos,
        const int2*  __restrict__ idcs,
        const float* __restrict__ eq,
        const float* __restrict__ tol,
        float* __restrict__ partial, int n) {
    float sum = 0.0f;
    for (int i = blockIdx.x * NTHREADS + threadIdx.x; i < n;
         i += gridDim.x * NTHREADS) {
        const int2 id = idcs[i];
        const float* p0 = pos + 3 * id.x;
        const float* p1 = pos + 3 * id.y;
        const float dx = p0[0] - p1[0];
        const float dy = p0[1] - p1[1];
        const float dz = p0[2] - p1[2];
        const float d  = sqrtf(dx * dx + dy * dy + dz * dz);
        const float r  = d - eq[i];
        const float t  = tol[i];
        sum += fmaxf(r * r - t * t, 0.0f);
    }
    sum = blockReduceSum(sum);
    if (threadIdx.x == 0) partial[blockIdx.x] = sum;
}

// ---------------------------------------------------------------------------
// Angles: a = acos(clip(dot(n0,n1))), E_i = relu((a - eq)^2 - tol^2)
// ---------------------------------------------------------------------------
__global__ __launch_bounds__(NTHREADS) void angle_kernel(
        const float* __restrict__ pos,
        const int*   __restrict__ idcs,
        const float* __restrict__ eq,
        const float* __restrict__ tol,
        float* __restrict__ partial, int n) {
    float sum = 0.0f;
    for (int i = blockIdx.x * NTHREADS + threadIdx.x; i < n;
         i += gridDim.x * NTHREADS) {
        const int ia = idcs[3 * i + 0];
        const int ib = idcs[3 * i + 1];
        const int ic = idcs[3 * i + 2];
        const float* pa = pos + 3 * ia;
        const float* pb = pos + 3 * ib;
        const float* pc = pos + 3 * ic;
        float b0x = pa[0] - pb[0], b0y = pa[1] - pb[1], b0z = pa[2] - pb[2];
        float b1x = pc[0] - pb[0], b1y = pc[1] - pb[1], b1z = pc[2] - pb[2];
        const float inv0 = rsqrtf(b0x * b0x + b0y * b0y + b0z * b0z);
        const float inv1 = rsqrtf(b1x * b1x + b1y * b1y + b1z * b1z);
        float c = (b0x * b1x + b0y * b1y + b0z * b1z) * inv0 * inv1;
        c = fminf(fmaxf(c, -1.0f + 1e-7f), 1.0f - 1e-7f);
        const float a = acosf(c);
        const float r = a - eq[i];
        const float t = tol[i];
        sum += fmaxf(r * r - t * t, 0.0f);
    }
    sum = blockReduceSum(sum);
    if (threadIdx.x == 0) partial[blockIdx.x] = sum;
}

// ---------------------------------------------------------------------------
// Dihedrals. dih = atan2(y, x).  dd = dih - eq.
// E_i = 2 + cos(dd - pi) + sin(dd - pi/2) = 2 - 2*cos(dd)
// cos(dd) = cos(atan2(y,x) - eq) = (x*cos(eq) + y*sin(eq)) / sqrt(x^2+y^2)
// -> no atan2 needed.
// ---------------------------------------------------------------------------
__global__ __launch_bounds__(NTHREADS) void dih_kernel(
        const float* __restrict__ pos,
        const int4*  __restrict__ idcs,
        const float* __restrict__ eq,
        float* __restrict__ partial, int n) {
    float sum = 0.0f;
    for (int i = blockIdx.x * NTHREADS + threadIdx.x; i < n;
         i += gridDim.x * NTHREADS) {
        const int4 id = idcs[i];
        const float* p0 = pos + 3 * id.x;
        const float* p1 = pos + 3 * id.y;
        const float* p2 = pos + 3 * id.z;
        const float* p3 = pos + 3 * id.w;
        float b0x = p0[0] - p1[0], b0y = p0[1] - p1[1], b0z = p0[2] - p1[2];
        float b1x = p2[0] - p1[0], b1y = p2[1] - p1[1], b1z = p2[2] - p1[2];
        float b2x = p3[0] - p2[0], b2y = p3[1] - p2[1], b2z = p3[2] - p2[2];
        const float inv1 = rsqrtf(b1x * b1x + b1y * b1y + b1z * b1z);
        b1x *= inv1; b1y *= inv1; b1z *= inv1;
        const float d01 = b0x * b1x + b0y * b1y + b0z * b1z;
        const float d21 = b2x * b1x + b2y * b1y + b2z * b1z;
        const float vx = b0x - d01 * b1x;
        const float vy = b0y - d01 * b1y;
        const float vz = b0z - d01 * b1z;
        const float wx = b2x - d21 * b1x;
        const float wy = b2y - d21 * b1y;
        const float wz = b2z - d21 * b1z;
        const float x = vx * wx + vy * wy + vz * wz;
        // cross(b1, v)
        const float cx = b1y * vz - b1z * vy;
        const float cy = b1z * vx - b1x * vz;
        const float cz = b1x * vy - b1y * vx;
        const float y = cx * wx + cy * wy + cz * wz;
        float se, ce;
        sincosf(eq[i], &se, &ce);
        const float invr = rsqrtf(fmaxf(x * x + y * y, 1e-30f));
        const float cosdd = (x * ce + y * se) * invr;
        sum += 2.0f - 2.0f * cosdd;
    }
    sum = blockReduceSum(sum);
    if (threadIdx.x == 0) partial[blockIdx.x] = sum;
}

// ---------------------------------------------------------------------------
// Finalize: reduce the 3 x NBLOCKS partials, scale, emit 4 outputs:
// [total, bond, angle, dihedral]
// ---------------------------------------------------------------------------
__global__ __launch_bounds__(NTHREADS) void finalize_kernel(
        const float* __restrict__ part,
        float* __restrict__ out,
        int nBond, int nAngle, int nDih) {
    float s0 = 0.0f, s1 = 0.0f, s2 = 0.0f;
    for (int i = threadIdx.x; i < NBLOCKS; i += NTHREADS) {
        s0 += part[i];
        s1 += part[NBLOCKS + i];
        s2 += part[2 * NBLOCKS + i];
    }
    s0 = blockReduceSum(s0);
    s1 = blockReduceSum(s1);
    s2 = blockReduceSum(s2);
    if (threadIdx.x == 0) {
        const float bond  = 1000.0f * s0 / (float)nBond;
        const float angle = 150.0f  * s1 / (float)nAngle;
        const float dih   = s2 / (float)nDih;
        out[0] = bond + angle + dih;
        out[1] = bond;
        out[2] = angle;
        out[3] = dih;
    }
}

extern "C" void kernel_launch(void* const* d_in, const int* in_sizes, int n_in,
                              void* d_out, int out_size, void* d_ws, size_t ws_size,
                              hipStream_t stream) {
    const float* pos      = (const float*)d_in[0];
    const int2*  bondIdcs = (const int2*)d_in[1];
    const float* bondEq   = (const float*)d_in[2];
    const float* bondTol  = (const float*)d_in[3];
    const int*   angIdcs  = (const int*)d_in[4];
    const float* angEq    = (const float*)d_in[5];
    const float* angTol   = (const float*)d_in[6];
    const int4*  dihIdcs  = (const int4*)d_in[7];
    const float* dihEq    = (const float*)d_in[8];

    const int nBond  = in_sizes[2];
    const int nAngle = in_sizes[5];
    const int nDih   = in_sizes[8];

    float* partial = (float*)d_ws;          // 3 * NBLOCKS floats
    float* out     = (float*)d_out;

    bond_kernel<<<NBLOCKS, NTHREADS, 0, stream>>>(
        pos, bondIdcs, bondEq, bondTol, partial, nBond);
    angle_kernel<<<NBLOCKS, NTHREADS, 0, stream>>>(
        pos, angIdcs, angEq, angTol, partial + NBLOCKS, nAngle);
    dih_kernel<<<NBLOCKS, NTHREADS, 0, stream>>>(
        pos, dihIdcs, dihEq, partial + 2 * NBLOCKS, nDih);
    finalize_kernel<<<1, NTHREADS, 0, stream>>>(
        partial, out, nBond, nAngle, nDih);
}

// Round 2
// 180.243 us; speedup vs baseline: 1.0259x; 1.0259x over previous
//
#include <hip/hip_runtime.h>
#include <math.h>

#define NTHREADS 256
#define NWAVES (NTHREADS / 64)
#define B_BOND 1024
#define B_ANG  2048
#define B_DIH  1024
#define NBLOCKS (B_BOND + B_ANG + B_DIH)

// ---------------------------------------------------------------------------
// Block-wide float sum. Wave=64 shuffle reduce, then LDS across waves.
// Only threadIdx.x==0 holds the full sum on return.
// ---------------------------------------------------------------------------
__device__ __forceinline__ float blockReduceSum(float v) {
    #pragma unroll
    for (int off = 32; off > 0; off >>= 1)
        v += __shfl_down(v, off, 64);
    __shared__ float s[NWAVES];
    const int lane = threadIdx.x & 63;
    const int wid  = threadIdx.x >> 6;
    if (lane == 0) s[wid] = v;
    __syncthreads();
    if (wid == 0) {
        v = (lane < NWAVES) ? s[lane] : 0.0f;
        #pragma unroll
        for (int off = NWAVES / 2; off > 0; off >>= 1)
            v += __shfl_down(v, off, 64);
    }
    return v;
}

// 12-byte vector load of one atom position -> global_load_dwordx3
__device__ __forceinline__ float3 ldpos(const float* __restrict__ pos, int atom) {
    return *reinterpret_cast<const float3*>(pos + 3 * atom);
}

// ---------------------------------------------------------------------------
// Fused kernel: block ranges handle bonds / angles / dihedrals.
// Each block writes one partial sum (deterministic, no atomics).
// ---------------------------------------------------------------------------
__global__ __launch_bounds__(NTHREADS) void fused_energy_kernel(
        const float* __restrict__ pos,
        const int2*  __restrict__ bondIdcs,
        const float* __restrict__ bondEq,
        const float* __restrict__ bondTol,
        const int*   __restrict__ angIdcs,
        const float* __restrict__ angEq,
        const float* __restrict__ angTol,
        const int4*  __restrict__ dihIdcs,
        const float* __restrict__ dihEq,
        float* __restrict__ partial,
        int nBond, int nAngle, int nDih) {
    float sum = 0.0f;

    if (blockIdx.x < B_BOND) {
        // ------------------------- bonds -------------------------
        const int stride = B_BOND * NTHREADS;
        #pragma unroll 4
        for (int i = blockIdx.x * NTHREADS + threadIdx.x; i < nBond; i += stride) {
            const int2 id = bondIdcs[i];
            const float3 a = ldpos(pos, id.x);
            const float3 b = ldpos(pos, id.y);
            const float dx = a.x - b.x, dy = a.y - b.y, dz = a.z - b.z;
            const float d  = sqrtf(dx * dx + dy * dy + dz * dz);
            const float r  = d - __builtin_nontemporal_load(bondEq + i);
            const float t  = __builtin_nontemporal_load(bondTol + i);
            sum += fmaxf(r * r - t * t, 0.0f);
        }
    } else if (blockIdx.x < B_BOND + B_ANG) {
        // ------------------------- angles ------------------------
        const int stride = B_ANG * NTHREADS;
        #pragma unroll 4
        for (int i = (blockIdx.x - B_BOND) * NTHREADS + threadIdx.x; i < nAngle;
             i += stride) {
            const int3 id = *reinterpret_cast<const int3*>(angIdcs + 3 * i);
            const float3 pa = ldpos(pos, id.x);
            const float3 pb = ldpos(pos, id.y);
            const float3 pc = ldpos(pos, id.z);
            const float b0x = pa.x - pb.x, b0y = pa.y - pb.y, b0z = pa.z - pb.z;
            const float b1x = pc.x - pb.x, b1y = pc.y - pb.y, b1z = pc.z - pb.z;
            const float inv0 = rsqrtf(b0x * b0x + b0y * b0y + b0z * b0z);
            const float inv1 = rsqrtf(b1x * b1x + b1y * b1y + b1z * b1z);
            float c = (b0x * b1x + b0y * b1y + b0z * b1z) * inv0 * inv1;
            c = fminf(fmaxf(c, -1.0f + 1e-7f), 1.0f - 1e-7f);
            const float a = acosf(c);
            const float r = a - __builtin_nontemporal_load(angEq + i);
            const float t = __builtin_nontemporal_load(angTol + i);
            sum += fmaxf(r * r - t * t, 0.0f);
        }
    } else {
        // ----------------------- dihedrals -----------------------
        const int stride = B_DIH * NTHREADS;
        #pragma unroll 4
        for (int i = (blockIdx.x - B_BOND - B_ANG) * NTHREADS + threadIdx.x;
             i < nDih; i += stride) {
            const int4 id = dihIdcs[i];
            const float3 p0 = ldpos(pos, id.x);
            const float3 p1 = ldpos(pos, id.y);
            const float3 p2 = ldpos(pos, id.z);
            const float3 p3 = ldpos(pos, id.w);
            const float b0x = p0.x - p1.x, b0y = p0.y - p1.y, b0z = p0.z - p1.z;
            float b1x = p2.x - p1.x, b1y = p2.y - p1.y, b1z = p2.z - p1.z;
            const float b2x = p3.x - p2.x, b2y = p3.y - p2.y, b2z = p3.z - p2.z;
            const float inv1 = rsqrtf(b1x * b1x + b1y * b1y + b1z * b1z);
            b1x *= inv1; b1y *= inv1; b1z *= inv1;
            const float d01 = b0x * b1x + b0y * b1y + b0z * b1z;
            const float d21 = b2x * b1x + b2y * b1y + b2z * b1z;
            const float vx = b0x - d01 * b1x;
            const float vy = b0y - d01 * b1y;
            const float vz = b0z - d01 * b1z;
            const float wx = b2x - d21 * b1x;
            const float wy = b2y - d21 * b1y;
            const float wz = b2z - d21 * b1z;
            const float x = vx * wx + vy * wy + vz * wz;
            const float cx = b1y * vz - b1z * vy;
            const float cy = b1z * vx - b1x * vz;
            const float cz = b1x * vy - b1y * vx;
            const float y = cx * wx + cy * wy + cz * wz;
            float se, ce;
            sincosf(__builtin_nontemporal_load(dihEq + i), &se, &ce);
            const float invr = rsqrtf(fmaxf(x * x + y * y, 1e-30f));
            const float cosdd = (x * ce + y * se) * invr;
            sum += 2.0f - 2.0f * cosdd;
        }
    }

    sum = blockReduceSum(sum);
    if (threadIdx.x == 0) partial[blockIdx.x] = sum;
}

// ---------------------------------------------------------------------------
// Finalize: reduce the per-block partials, scale, emit 4 outputs:
// [total, bond, angle, dihedral]
// ---------------------------------------------------------------------------
__global__ __launch_bounds__(NTHREADS) void finalize_kernel(
        const float* __restrict__ part,
        float* __restrict__ out,
        int nBond, int nAngle, int nDih) {
    float s0 = 0.0f, s1 = 0.0f, s2 = 0.0f;
    for (int i = threadIdx.x; i < B_BOND; i += NTHREADS)
        s0 += part[i];
    for (int i = threadIdx.x; i < B_ANG; i += NTHREADS)
        s1 += part[B_BOND + i];
    for (int i = threadIdx.x; i < B_DIH; i += NTHREADS)
        s2 += part[B_BOND + B_ANG + i];
    s0 = blockReduceSum(s0);
    __syncthreads();
    s1 = blockReduceSum(s1);
    __syncthreads();
    s2 = blockReduceSum(s2);
    if (threadIdx.x == 0) {
        const float bond  = 1000.0f * s0 / (float)nBond;
        const float angle = 150.0f  * s1 / (float)nAngle;
        const float dih   = s2 / (float)nDih;
        out[0] = bond + angle + dih;
        out[1] = bond;
        out[2] = angle;
        out[3] = dih;
    }
}

extern "C" void kernel_launch(void* const* d_in, const int* in_sizes, int n_in,
                              void* d_out, int out_size, void* d_ws, size_t ws_size,
                              hipStream_t stream) {
    const float* pos      = (const float*)d_in[0];
    const int2*  bondIdcs = (const int2*)d_in[1];
    const float* bondEq   = (const float*)d_in[2];
    const float* bondTol  = (const float*)d_in[3];
    const int*   angIdcs  = (const int*)d_in[4];
    const float* angEq    = (const float*)d_in[5];
    const float* angTol   = (const float*)d_in[6];
    const int4*  dihIdcs  = (const int4*)d_in[7];
    const float* dihEq    = (const float*)d_in[8];

    const int nBond  = in_sizes[2];
    const int nAngle = in_sizes[5];
    const int nDih   = in_sizes[8];

    float* partial = (float*)d_ws;          // NBLOCKS floats
    float* out     = (float*)d_out;

    fused_energy_kernel<<<NBLOCKS, NTHREADS, 0, stream>>>(
        pos, bondIdcs, bondEq, bondTol,
        angIdcs, angEq, angTol,
        dihIdcs, dihEq,
        partial, nBond, nAngle, nDih);
    finalize_kernel<<<1, NTHREADS, 0, stream>>>(
        partial, out, nBond, nAngle, nDih);
}